// Round 10
// baseline (814.359 us; speedup 1.0000x reference)
//
#include <hip/hip_runtime.h>
#include <hip/hip_bf16.h>
#include <stdint.h>

#define N_NODES 100000
#define N_EDGES 3200000
#define IN_CH 256
#define HID 128
#define EPS 1e-5f
#define BSH 9              // bucket = dst >> 9  (512 nodes per bucket)
#define NBUK 196           // ceil(100000/512)
#define PCHUNK 4096
#define GEMM_GRID 782      // ceil(100000/128)
#define SEGSH 14           // src segment = src >> 14 (segments 0..6)

using bf16x8 = __attribute__((ext_vector_type(8))) short;
using f32x4  = __attribute__((ext_vector_type(4))) float;
using f32x2  = __attribute__((ext_vector_type(2))) float;

__device__ __forceinline__ uint32_t f2bf(float f) {
  uint32_t u = __float_as_uint(f);
  return (u + 0x7FFFu + ((u >> 16) & 1u)) >> 16;
}
__device__ __forceinline__ float bflo(uint32_t u) { return __uint_as_float(u << 16); }
__device__ __forceinline__ float bfhi(uint32_t u) { return __uint_as_float(u & 0xFFFF0000u); }

// ---- workspace layout (bytes), all 128-aligned ----
static const size_t OFF_SRC   = 0;            // int[3.2M] CSR src = 12,800,000
static const size_t OFF_OFFS  = 12800000;     // int[800001] fine offsets = 3,200,004 (+pad)
static const size_t OFF_DINV  = 16000128;     // float[100000]
static const size_t OFF_WPK0  = 16400128;     // 65,536
static const size_t OFF_WPK1  = 16465664;     // 32,768
static const size_t OFF_WPK2  = 16498432;     // 32,768
static const size_t OFF_WPKR  = 16531200;     // 65,536
static const size_t OFF_FLAG  = 16596736;     // int (+pad)
static const size_t OFF_BCNT  = 16596864;     // int[NBUK]
static const size_t OFF_BBASE = 16597888;     // int[NBUK+1]
static const size_t OFF_BCUR  = 16598912;     // int[NBUK]
static const size_t OFF_H8    = 16599936;     // fp8[100000*128] = 12,800,000
static const size_t OFF_PART  = 16599936;     // int2[3.2M] = 25.6MB (aliases H8; dead before GEMM)
static const size_t OFF_RESB  = 42199936;     // bf16[100000*128] = 25,600,000
static const size_t OFF_HBA   = 67799936;     // bf16[100000*128]
static const size_t OFF_HBB   = 93399936;     // bf16[100000*128]  (end ~119MB)

// ---- edge dtype detection: int64 edges have zero high words ----
__global__ void k_flag(const uint32_t* __restrict__ e, int* flag) {
  __shared__ int any;
  if (threadIdx.x == 0) any = 0;
  __syncthreads();
  uint32_t acc = 0;
  for (int i = threadIdx.x; i < 2048; i += blockDim.x) acc |= e[2 * i + 1];
  if (acc) atomicOr(&any, 1);
  __syncthreads();
  if (threadIdx.x == 0) *flag = (any == 0) ? 1 : 0;  // 1 => int64 layout
}

// ---- bucket histogram (LDS-aggregated) ----
__global__ __launch_bounds__(256) void k_hist(const void* __restrict__ eidx,
                                              const int* __restrict__ flag,
                                              int* __restrict__ bcnt) {
  __shared__ int h[NBUK];
  for (int t = threadIdx.x; t < NBUK; t += 256) h[t] = 0;
  __syncthreads();
  bool i64 = (*flag != 0);
  int stride = gridDim.x * blockDim.x;
  for (int e = blockIdx.x * blockDim.x + threadIdx.x; e < N_EDGES; e += stride) {
    int d = i64 ? (int)((const uint32_t*)eidx)[2 * ((size_t)N_EDGES + e)]
                : ((const int*)eidx)[N_EDGES + e];
    atomicAdd(&h[d >> BSH], 1);
  }
  __syncthreads();
  for (int t = threadIdx.x; t < NBUK; t += 256)
    if (h[t]) atomicAdd(&bcnt[t], h[t]);
}

// ---- serial bucket scan (196 elems); also terminal fine-offset ----
__global__ void k_bscan(const int* __restrict__ bcnt, int* __restrict__ bbase,
                        int* __restrict__ bcur, int* __restrict__ offsF) {
  if (threadIdx.x == 0 && blockIdx.x == 0) {
    int run = 0;
    for (int b = 0; b < NBUK; ++b) {
      bbase[b] = run;
      bcur[b] = run;
      run += bcnt[b];
    }
    bbase[NBUK] = run;
    offsF[N_NODES * 8] = run;
  }
}

// ---- LDS-staged partition into buckets (coalesced writes) ----
__global__ __launch_bounds__(256) void k_part(const void* __restrict__ eidx,
                                              const int* __restrict__ flag,
                                              int* __restrict__ bcur,
                                              int2* __restrict__ part) {
  __shared__ int lhist[NBUK];
  __shared__ int lbase[NBUK];
  __shared__ int gbase[NBUK];
  __shared__ int sm[256];
  __shared__ int2 sbuf[PCHUNK];
  __shared__ uint8_t bbuf[PCHUNK];
  int tid = threadIdx.x;
  int base = blockIdx.x * PCHUNK;
  int nE = N_EDGES - base;
  if (nE > PCHUNK) nE = PCHUNK;
  for (int t = tid; t < NBUK; t += 256) lhist[t] = 0;
  __syncthreads();
  bool i64 = (*flag != 0);
  int es[16], ed[16], ml[16];
  #pragma unroll
  for (int k = 0; k < 16; ++k) {
    int ci = k * 256 + tid;
    if (ci < nE) {
      int e = base + ci;
      int s, d;
      if (i64) {
        const uint32_t* u = (const uint32_t*)eidx;
        s = (int)u[2 * (size_t)e];
        d = (int)u[2 * ((size_t)N_EDGES + e)];
      } else {
        const int* u = (const int*)eidx;
        s = u[e];
        d = u[N_EDGES + e];
      }
      es[k] = s; ed[k] = d;
      ml[k] = atomicAdd(&lhist[d >> BSH], 1);
    }
  }
  __syncthreads();
  sm[tid] = (tid < NBUK) ? lhist[tid] : 0;
  __syncthreads();
  for (int s = 1; s < 256; s <<= 1) {
    int t = (tid >= s) ? sm[tid - s] : 0;
    __syncthreads();
    sm[tid] += t;
    __syncthreads();
  }
  if (tid < NBUK) lbase[tid] = sm[tid] - lhist[tid];
  __syncthreads();
  #pragma unroll
  for (int k = 0; k < 16; ++k) {
    int ci = k * 256 + tid;
    if (ci < nE) {
      int b = ed[k] >> BSH;
      int slot = lbase[b] + ml[k];
      sbuf[slot] = make_int2(es[k], ed[k]);
      bbuf[slot] = (uint8_t)b;
    }
  }
  if (tid < NBUK && lhist[tid] > 0) gbase[tid] = atomicAdd(&bcur[tid], lhist[tid]);
  __syncthreads();
  for (int i = tid; i < nE; i += 256) {
    int b = bbuf[i];
    part[(size_t)gbase[b] + (i - lbase[b])] = sbuf[i];
  }
}

// ---- bucketB: (node,seg)-keyed counting sort -> fine offsets + dinv + CSR ----
__global__ __launch_bounds__(256) void k_bucketB(const int2* __restrict__ part,
                                                 const int* __restrict__ bbase,
                                                 int* __restrict__ offsF,
                                                 float* __restrict__ dinv,
                                                 int* __restrict__ sedge) {
  __shared__ int cnt[4096];
  __shared__ int s2[256];
  int tid = threadIdx.x, b = blockIdx.x;
  int v0 = b << BSH;
  int e0 = bbase[b], e1 = bbase[b + 1];
  for (int i = tid; i < 4096; i += 256) cnt[i] = 0;
  __syncthreads();
  for (int i = e0 + tid; i < e1; i += 256) {
    int2 e = part[i];
    atomicAdd(&cnt[((e.y - v0) << 3) | (e.x >> SEGSH)], 1);
  }
  __syncthreads();
  // exclusive scan of 4096 keys (16 per thread, contiguous)
  int loc[16];
  int base = tid * 16, sum = 0;
  #pragma unroll
  for (int k = 0; k < 16; ++k) { loc[k] = cnt[base + k]; sum += loc[k]; }
  s2[tid] = sum;
  __syncthreads();
  for (int s = 1; s < 256; s <<= 1) {
    int t = (tid >= s) ? s2[tid - s] : 0;
    __syncthreads();
    s2[tid] += t;
    __syncthreads();
  }
  int run = s2[tid] - sum;
  #pragma unroll
  for (int k = 0; k < 16; ++k) { cnt[base + k] = run; run += loc[k]; }
  // dinv: thread covers nodes v0+2tid (keys 0..7) and v0+2tid+1 (keys 8..15)
  {
    int c0 = 0, c1 = 0;
    #pragma unroll
    for (int k = 0; k < 8; ++k) { c0 += loc[k]; c1 += loc[k + 8]; }
    int va = v0 + 2 * tid, vb = va + 1;
    if (va < N_NODES) dinv[va] = rsqrtf((float)(c0 + 1));
    if (vb < N_NODES) dinv[vb] = rsqrtf((float)(c1 + 1));
  }
  __syncthreads();
  // fine offsets: offsF[v0*8 + i] = e0 + start(key i)   (entry 7 == node end, since seg<=6)
  for (int i = tid; i < 4096; i += 256) {
    if (v0 + (i >> 3) < N_NODES) offsF[v0 * 8 + i] = e0 + cnt[i];
  }
  // scatter (cnt as cursor)
  for (int i = e0 + tid; i < e1; i += 256) {
    int2 e = part[i];
    int key = ((e.y - v0) << 3) | (e.x >> SEGSH);
    int p = atomicAdd(&cnt[key], 1);
    sedge[e0 + p] = e.x;
  }
}

// pack W [K][HID] f32 row-major into MFMA B-fragment-ready bf16 layout
__global__ void k_packW(const float* __restrict__ W, uint16_t* __restrict__ Wp, int K) {
  int t = blockIdx.x * blockDim.x + threadIdx.x;
  int total = (K / 32) * 8 * 64;
  if (t >= total) return;
  int l = t & 63;
  int nt = (t >> 6) & 7;
  int ks = t >> 9;
  int kbase = ks * 32 + (l >> 4) * 8;
  int col = nt * 16 + (l & 15);
  #pragma unroll
  for (int j = 0; j < 8; ++j)
    Wp[(size_t)t * 8 + j] = (uint16_t)f2bf(W[(size_t)(kbase + j) * HID + col]);
}

// epilogue: store h' = dinv[row] * acc as fp8 e4m3 rows, via swizzled LDS repack
__device__ __forceinline__ void epilogue_fp8(const f32x4* acc, int l, int row0,
                                             uint8_t* lds_my,
                                             uint8_t* __restrict__ H8,
                                             const float* __restrict__ dinv) {
  float dv[4];
  #pragma unroll
  for (int j = 0; j < 4; ++j) {
    int r = row0 + (l >> 4) * 4 + j;
    dv[j] = dinv[min(r, N_NODES - 1)];
  }
  #pragma unroll
  for (int nt = 0; nt < 8; ++nt)
    #pragma unroll
    for (int j = 0; j < 4; ++j) {
      int r = (l >> 4) * 4 + j, c = nt * 16 + (l & 15);
      uint32_t pk = __builtin_amdgcn_cvt_pk_fp8_f32(acc[nt][j] * dv[j], 0.f, 0u, false);
      lds_my[r * 128 + (c ^ ((r & 7) << 2))] = (uint8_t)pk;  // 4B-granule swizzle by row
    }
  asm volatile("s_waitcnt lgkmcnt(0)" ::: "memory");
  int r = l >> 2;
  uint32_t w[8];
  #pragma unroll
  for (int t = 0; t < 8; ++t) {
    int c4 = (l & 3) * 8 + t;
    w[t] = *(const uint32_t*)(lds_my + r * 128 + ((c4 ^ (r & 7)) << 2));
  }
  if (row0 + r < N_NODES) {
    uint4* gp = (uint4*)(H8 + (size_t)(row0 + r) * 128 + (l & 3) * 32);
    gp[0] = make_uint4(w[0], w[1], w[2], w[3]);
    gp[1] = make_uint4(w[4], w[5], w[6], w[7]);
  }
  asm volatile("s_waitcnt lgkmcnt(0)" ::: "memory");
}

// layer-0 fused dual GEMM in one launch: blocks [0,782) do X@W0 -> fp8 h';
// blocks [782,1564) do X@Wr -> bf16 residual. f32 A read + in-flight cvt.
__global__ __launch_bounds__(256) void k_gemm0d(const float* __restrict__ X,
                                                const uint16_t* __restrict__ Wp0,
                                                const uint16_t* __restrict__ WpR,
                                                uint8_t* __restrict__ H8,
                                                const float* __restrict__ dinv,
                                                uint16_t* __restrict__ resB) {
  __shared__ __align__(16) char smem[32768];
  int tid = threadIdx.x, wid = tid >> 6, l = tid & 63;
  bool second = blockIdx.x >= GEMM_GRID;
  int blk = second ? (blockIdx.x - GEMM_GRID) : blockIdx.x;
  const uint16_t* Wp = second ? WpR : Wp0;
  int r0 = blk * 128 + wid * 32;
  int hk = l >> 4, rl = l & 15;
  int ra0 = min(r0 + rl, N_NODES - 1);
  int ra1 = min(r0 + 16 + rl, N_NODES - 1);
  f32x4 acc[2][8] = {};
  #pragma unroll
  for (int kh = 0; kh < 2; ++kh) {
    __syncthreads();
    #pragma unroll
    for (int i = 0; i < 8; ++i) {
      int gidx = i * 256 + tid;
      *(uint4*)(smem + gidx * 16) =
          *(const uint4*)((const char*)Wp + (size_t)kh * 32768 + gidx * 16);
    }
    __syncthreads();
    #pragma unroll
    for (int ksl = 0; ksl < 4; ++ksl) {
      int kof = kh * 128 + ksl * 32 + hk * 8;
      float4 u0 = *(const float4*)(X + (size_t)ra0 * 256 + kof);
      float4 u1 = *(const float4*)(X + (size_t)ra0 * 256 + kof + 4);
      float4 w0 = *(const float4*)(X + (size_t)ra1 * 256 + kof);
      float4 w1 = *(const float4*)(X + (size_t)ra1 * 256 + kof + 4);
      bf16x8 a0, a1;
      a0[0] = (short)f2bf(u0.x); a0[1] = (short)f2bf(u0.y);
      a0[2] = (short)f2bf(u0.z); a0[3] = (short)f2bf(u0.w);
      a0[4] = (short)f2bf(u1.x); a0[5] = (short)f2bf(u1.y);
      a0[6] = (short)f2bf(u1.z); a0[7] = (short)f2bf(u1.w);
      a1[0] = (short)f2bf(w0.x); a1[1] = (short)f2bf(w0.y);
      a1[2] = (short)f2bf(w0.z); a1[3] = (short)f2bf(w0.w);
      a1[4] = (short)f2bf(w1.x); a1[5] = (short)f2bf(w1.y);
      a1[6] = (short)f2bf(w1.z); a1[7] = (short)f2bf(w1.w);
      #pragma unroll
      for (int nt = 0; nt < 8; ++nt) {
        bf16x8 b = *(const bf16x8*)(smem + ((ksl * 8 + nt) * 64 + l) * 16);
        acc[0][nt] = __builtin_amdgcn_mfma_f32_16x16x32_bf16(a0, b, acc[0][nt], 0, 0, 0);
        acc[1][nt] = __builtin_amdgcn_mfma_f32_16x16x32_bf16(a1, b, acc[1][nt], 0, 0, 0);
      }
    }
  }
  __syncthreads();  // B dead; per-wave epilogue scratch (8KB each)
  if (!second) {
    uint8_t* lds8 = (uint8_t*)(smem + wid * 8192);
    epilogue_fp8(acc[0], l, r0, lds8, H8, dinv);
    epilogue_fp8(acc[1], l, r0 + 16, lds8, H8, dinv);
  } else {
    uint16_t* ldsb = (uint16_t*)(smem + wid * 8192);
    #pragma unroll
    for (int rt = 0; rt < 2; ++rt) {
      int row0 = r0 + rt * 16;
      #pragma unroll
      for (int nt = 0; nt < 8; ++nt)
        #pragma unroll
        for (int j = 0; j < 4; ++j)
          ldsb[((l >> 4) * 4 + j) * 128 + nt * 16 + (l & 15)] = (uint16_t)f2bf(acc[rt][nt][j]);
      asm volatile("s_waitcnt lgkmcnt(0)" ::: "memory");
      const uint4* sb = (const uint4*)ldsb;
      if (row0 + (l >> 2) < N_NODES) {
        uint4* gb = (uint4*)(resB + (size_t)(row0 + (l >> 2)) * 128 + (l & 3) * 32);
        #pragma unroll
        for (int t = 0; t < 4; ++t) gb[t] = sb[l * 4 + t];
      }
      asm volatile("s_waitcnt lgkmcnt(0)" ::: "memory");
    }
  }
}

// layers 1/2 GEMM: A bf16 [N][128] @ Wp(LDS-shared) -> fp8 h'
__global__ __launch_bounds__(256) void k_gemm8(const uint16_t* __restrict__ A,
                                               const uint16_t* __restrict__ Wp,
                                               uint8_t* __restrict__ H8,
                                               const float* __restrict__ dinv) {
  __shared__ __align__(16) char smem[32768];
  int tid = threadIdx.x, wid = tid >> 6, l = tid & 63;
  #pragma unroll
  for (int i = 0; i < 8; ++i) {
    int gidx = i * 256 + tid;
    *(uint4*)(smem + gidx * 16) = *(const uint4*)((const char*)Wp + gidx * 16);
  }
  __syncthreads();
  int r0 = blockIdx.x * 128 + wid * 32;
  int hk = l >> 4, rl = l & 15;
  int ra0 = min(r0 + rl, N_NODES - 1);
  int ra1 = min(r0 + 16 + rl, N_NODES - 1);
  f32x4 acc[2][8] = {};
  #pragma unroll
  for (int ks = 0; ks < 4; ++ks) {
    bf16x8 a0 = *(const bf16x8*)(A + (size_t)ra0 * 128 + ks * 32 + hk * 8);
    bf16x8 a1 = *(const bf16x8*)(A + (size_t)ra1 * 128 + ks * 32 + hk * 8);
    #pragma unroll
    for (int nt = 0; nt < 8; ++nt) {
      bf16x8 b = *(const bf16x8*)(smem + ((ks * 8 + nt) * 64 + l) * 16);
      acc[0][nt] = __builtin_amdgcn_mfma_f32_16x16x32_bf16(a0, b, acc[0][nt], 0, 0, 0);
      acc[1][nt] = __builtin_amdgcn_mfma_f32_16x16x32_bf16(a1, b, acc[1][nt], 0, 0, 0);
    }
  }
  __syncthreads();  // B dead; reuse as epilogue scratch
  uint8_t* lds8 = (uint8_t*)(smem + wid * 4096);
  epilogue_fp8(acc[0], l, r0, lds8, H8, dinv);
  epilogue_fp8(acc[1], l, r0 + 16, lds8, H8, dinv);
}

// fused: fp8 gather-sum + bias + LN + ReLU + bf16 residual.
// Wave owns 4 nodes; lane owns channels 2l,2l+1 of all 4 (full row spread across wave).
// Outer loop sweeps src segments (2MB H8 windows) -- chip-wide L2 locality.
#define EDGE1(EV, AN)                                                   \
  do {                                                                  \
    uint32_t h_ = *(const uint16_t*)(H8 + ((uint32_t)(EV) << 7) + ch);  \
    f32x2 f_ = __builtin_amdgcn_cvt_pk_f32_fp8(h_, false);              \
    asm("v_pk_add_f32 %0, %0, %1" : "+v"(AN) : "v"(f_));                \
  } while (0)

__global__ __launch_bounds__(256) void k_agg(const uint8_t* __restrict__ H8,
                                             const int* __restrict__ sedge,
                                             const int* __restrict__ offsF,
                                             const float* __restrict__ dinv,
                                             const float* __restrict__ bias,
                                             const float* __restrict__ g,
                                             const float* __restrict__ be,
                                             const uint16_t* __restrict__ residB,
                                             float* __restrict__ outF,
                                             uint16_t* __restrict__ outB) {
  int wid = threadIdx.x >> 6, l = threadIdx.x & 63;
  int vbase = (blockIdx.x * 4 + wid) * 4;
  if (vbase >= N_NODES) return;
  uint32_t ch = (uint32_t)(2 * l);
  f32x2 acc[4] = {{0.f, 0.f}, {0.f, 0.f}, {0.f, 0.f}, {0.f, 0.f}};
  #pragma unroll 1
  for (int seg = 0; seg < 7; ++seg) {
    #pragma unroll
    for (int n = 0; n < 4; ++n) {
      int v = vbase + n;
      int p = offsF[v * 8 + seg];
      int p1 = offsF[v * 8 + seg + 1];
      int i = p;
      for (; i + 3 < p1; i += 4) {
        int e0 = sedge[i], e1 = sedge[i + 1], e2 = sedge[i + 2], e3 = sedge[i + 3];
        uint32_t h0 = *(const uint16_t*)(H8 + ((uint32_t)e0 << 7) + ch);
        uint32_t h1 = *(const uint16_t*)(H8 + ((uint32_t)e1 << 7) + ch);
        uint32_t h2 = *(const uint16_t*)(H8 + ((uint32_t)e2 << 7) + ch);
        uint32_t h3 = *(const uint16_t*)(H8 + ((uint32_t)e3 << 7) + ch);
        f32x2 f0 = __builtin_amdgcn_cvt_pk_f32_fp8(h0, false);
        f32x2 f1 = __builtin_amdgcn_cvt_pk_f32_fp8(h1, false);
        f32x2 f2 = __builtin_amdgcn_cvt_pk_f32_fp8(h2, false);
        f32x2 f3 = __builtin_amdgcn_cvt_pk_f32_fp8(h3, false);
        asm("v_pk_add_f32 %0, %0, %1" : "+v"(acc[n]) : "v"(f0));
        asm("v_pk_add_f32 %0, %0, %1" : "+v"(acc[n]) : "v"(f1));
        asm("v_pk_add_f32 %0, %0, %1" : "+v"(acc[n]) : "v"(f2));
        asm("v_pk_add_f32 %0, %0, %1" : "+v"(acc[n]) : "v"(f3));
      }
      for (; i < p1; ++i) {
        int e0 = sedge[i];
        EDGE1(e0, acc[n]);
      }
    }
  }
  // self loops + finish
  float2 bb = *(const float2*)(bias + ch);
  float2 gg = *(const float2*)(g + ch);
  float2 ee = *(const float2*)(be + ch);
  #pragma unroll
  for (int n = 0; n < 4; ++n) {
    int v = vbase + n;
    EDGE1((uint32_t)v, acc[n]);
    float dv = dinv[v];
    float x0 = dv * acc[n].x + bb.x;
    float x1 = dv * acc[n].y + bb.y;
    float s = x0 + x1;
    #pragma unroll
    for (int m = 1; m < 64; m <<= 1) s += __shfl_xor(s, m, 64);
    float mu = s * (1.f / 128.f);
    float d0 = x0 - mu, d1 = x1 - mu;
    float qq = d0 * d0 + d1 * d1;
    #pragma unroll
    for (int m = 1; m < 64; m <<= 1) qq += __shfl_xor(qq, m, 64);
    float rs = rsqrtf(qq * (1.f / 128.f) + EPS);
    float y0 = fmaxf(d0 * rs * gg.x + ee.x, 0.f);
    float y1 = fmaxf(d1 * rs * gg.y + ee.y, 0.f);
    uint32_t rr = *(const uint32_t*)(residB + (size_t)v * 128 + ch);
    y0 += bflo(rr);
    y1 += bfhi(rr);
    if (outF) *(float2*)(outF + (size_t)v * 128 + ch) = make_float2(y0, y1);
    if (outB) *(uint32_t*)(outB + (size_t)v * 128 + ch) = f2bf(y0) | (f2bf(y1) << 16);
  }
}

extern "C" void kernel_launch(void* const* d_in, const int* in_sizes, int n_in,
                              void* d_out, int out_size, void* d_ws, size_t ws_size,
                              hipStream_t stream) {
  const float* x   = (const float*)d_in[0];
  const void*  ei  = d_in[1];
  const float* W0  = (const float*)d_in[2];
  const float* b0  = (const float*)d_in[3];
  const float* g0  = (const float*)d_in[4];
  const float* be0 = (const float*)d_in[5];
  const float* W1  = (const float*)d_in[6];
  const float* b1  = (const float*)d_in[7];
  const float* g1  = (const float*)d_in[8];
  const float* be1 = (const float*)d_in[9];
  const float* W2  = (const float*)d_in[10];
  const float* b2  = (const float*)d_in[11];
  const float* g2  = (const float*)d_in[12];
  const float* be2 = (const float*)d_in[13];
  const float* Wr  = (const float*)d_in[14];

  char* ws = (char*)d_ws;
  int*      sedge  = (int*)(ws + OFF_SRC);
  int*      offsF  = (int*)(ws + OFF_OFFS);
  float*    dinv   = (float*)(ws + OFF_DINV);
  uint16_t* wpk0   = (uint16_t*)(ws + OFF_WPK0);
  uint16_t* wpk1   = (uint16_t*)(ws + OFF_WPK1);
  uint16_t* wpk2   = (uint16_t*)(ws + OFF_WPK2);
  uint16_t* wpkr   = (uint16_t*)(ws + OFF_WPKR);
  int*      flag   = (int*)(ws + OFF_FLAG);
  int*      bcnt   = (int*)(ws + OFF_BCNT);
  int*      bbase  = (int*)(ws + OFF_BBASE);
  int*      bcur   = (int*)(ws + OFF_BCUR);
  uint8_t*  h8     = (uint8_t*)(ws + OFF_H8);
  int2*     part   = (int2*)(ws + OFF_PART);
  uint16_t* resB   = (uint16_t*)(ws + OFF_RESB);
  uint16_t* hbA    = (uint16_t*)(ws + OFF_HBA);
  uint16_t* hbB    = (uint16_t*)(ws + OFF_HBB);
  float*    out    = (float*)d_out;

  // ---- edge preprocessing: hist -> scan -> partition -> per-bucket fine CSR ----
  k_flag<<<1, 256, 0, stream>>>((const uint32_t*)ei, flag);
  hipMemsetAsync(bcnt, 0, NBUK * sizeof(int), stream);
  k_hist<<<2048, 256, 0, stream>>>(ei, flag, bcnt);
  k_bscan<<<1, 64, 0, stream>>>(bcnt, bbase, bcur, offsF);
  k_part<<<(N_EDGES + PCHUNK - 1) / PCHUNK, 256, 0, stream>>>(ei, flag, bcur, part);
  k_bucketB<<<NBUK, 256, 0, stream>>>(part, bbase, offsF, dinv, sedge);

  // ---- weight packing ----
  k_packW<<<16, 256, 0, stream>>>(W0, wpk0, IN_CH);
  k_packW<<<8, 256, 0, stream>>>(W1, wpk1, HID);
  k_packW<<<8, 256, 0, stream>>>(W2, wpk2, HID);
  k_packW<<<16, 256, 0, stream>>>(Wr, wpkr, IN_CH);

  // ---- layer 0: fused dual K=256 GEMM launch (x@W0 -> fp8 h', x@Wr -> bf16 resid) ----
  k_gemm0d<<<2 * GEMM_GRID, 256, 0, stream>>>(x, wpk0, wpkr, h8, dinv, resB);
  k_agg<<<6250, 256, 0, stream>>>(h8, sedge, offsF, dinv, b0, g0, be0, resB, nullptr, hbA);

  // ---- layer 1 ----
  k_gemm8<<<GEMM_GRID, 256, 0, stream>>>(hbA, wpk1, h8, dinv);
  k_agg<<<6250, 256, 0, stream>>>(h8, sedge, offsF, dinv, b1, g1, be1, hbA, nullptr, hbB);

  // ---- layer 2 (writes d_out f32) ----
  k_gemm8<<<GEMM_GRID, 256, 0, stream>>>(hbB, wpk2, h8, dinv);
  k_agg<<<6250, 256, 0, stream>>>(h8, sedge, offsF, dinv, b2, g2, be2, hbB, out, nullptr);

  (void)in_sizes; (void)n_in; (void)out_size; (void)ws_size;
}

// Round 11
// 452.745 us; speedup vs baseline: 1.7987x; 1.7987x over previous
//
#include <hip/hip_runtime.h>
#include <hip/hip_bf16.h>
#include <stdint.h>

#define N_NODES 100000
#define N_EDGES 3200000
#define IN_CH 256
#define HID 128
#define EPS 1e-5f
#define BSH 9              // bucket = dst >> 9  (512 nodes per bucket)
#define NBUK 196           // ceil(100000/512)
#define PCHUNK 4096
#define GEMM_GRID 782      // ceil(100000/128)

using bf16x8 = __attribute__((ext_vector_type(8))) short;
using f32x4  = __attribute__((ext_vector_type(4))) float;
using f32x2  = __attribute__((ext_vector_type(2))) float;

__device__ __forceinline__ uint32_t f2bf(float f) {
  uint32_t u = __float_as_uint(f);
  return (u + 0x7FFFu + ((u >> 16) & 1u)) >> 16;
}
__device__ __forceinline__ float bflo(uint32_t u) { return __uint_as_float(u << 16); }
__device__ __forceinline__ float bfhi(uint32_t u) { return __uint_as_float(u & 0xFFFF0000u); }

// ---- workspace layout (bytes), all 128-aligned ----
static const size_t OFF_SRC   = 0;            // int[3,600,000] padded CSR src = 14,400,000
static const size_t OFF_OFFS  = 14400000;     // int[100001]
static const size_t OFF_DINV  = 14800128;     // float[100000]
static const size_t OFF_CNTG  = 15600256;     // int[100000]
static const size_t OFF_WPK0  = 16000256;     // 65,536
static const size_t OFF_WPK1  = 16065792;     // 32,768
static const size_t OFF_WPK2  = 16098560;     // 32,768
static const size_t OFF_WPKR  = 16131328;     // 65,536
static const size_t OFF_FLAG  = 16196864;     // int (+pad)
static const size_t OFF_BCNT  = 16196992;     // int[NBUK]
static const size_t OFF_BBASE = 16198016;     // int[NBUK+1]
static const size_t OFF_BCUR  = 16199040;     // int[NBUK]
static const size_t OFF_PTOT  = 16200064;     // int[NBUK]
static const size_t OFF_PBASE = 16201088;     // int[NBUK+1]
static const size_t OFF_H8    = 16202240;     // fp8[100001*128] = 12,800,128
static const size_t OFF_PART  = 16202240;     // int2[3.2M] = 25.6MB (aliases H8; dead before GEMM)
static const size_t OFF_RESB  = 41802240;     // bf16[100000*128] = 25,600,000
static const size_t OFF_HBA   = 67402240;     // bf16[100000*128]
static const size_t OFF_HBB   = 93002240;     // bf16[100000*128]  (end ~118.6MB)

// ---- edge dtype detection: int64 edges have zero high words ----
__global__ void k_flag(const uint32_t* __restrict__ e, int* flag) {
  __shared__ int any;
  if (threadIdx.x == 0) any = 0;
  __syncthreads();
  uint32_t acc = 0;
  for (int i = threadIdx.x; i < 2048; i += blockDim.x) acc |= e[2 * i + 1];
  if (acc) atomicOr(&any, 1);
  __syncthreads();
  if (threadIdx.x == 0) *flag = (any == 0) ? 1 : 0;  // 1 => int64 layout
}

// ---- bucket histogram (LDS-aggregated) ----
__global__ __launch_bounds__(256) void k_hist(const void* __restrict__ eidx,
                                              const int* __restrict__ flag,
                                              int* __restrict__ bcnt) {
  __shared__ int h[NBUK];
  for (int t = threadIdx.x; t < NBUK; t += 256) h[t] = 0;
  __syncthreads();
  bool i64 = (*flag != 0);
  int stride = gridDim.x * blockDim.x;
  for (int e = blockIdx.x * blockDim.x + threadIdx.x; e < N_EDGES; e += stride) {
    int d = i64 ? (int)((const uint32_t*)eidx)[2 * ((size_t)N_EDGES + e)]
                : ((const int*)eidx)[N_EDGES + e];
    atomicAdd(&h[d >> BSH], 1);
  }
  __syncthreads();
  for (int t = threadIdx.x; t < NBUK; t += 256)
    if (h[t]) atomicAdd(&bcnt[t], h[t]);
}

// ---- serial bucket scan (196 elems) ----
__global__ void k_bscan(const int* __restrict__ bcnt, int* __restrict__ bbase,
                        int* __restrict__ bcur) {
  if (threadIdx.x == 0 && blockIdx.x == 0) {
    int run = 0;
    for (int b = 0; b < NBUK; ++b) {
      bbase[b] = run;
      bcur[b] = run;
      run += bcnt[b];
    }
    bbase[NBUK] = run;
  }
}

// ---- LDS-staged partition into buckets (coalesced writes) ----
__global__ __launch_bounds__(256) void k_part(const void* __restrict__ eidx,
                                              const int* __restrict__ flag,
                                              int* __restrict__ bcur,
                                              int2* __restrict__ part) {
  __shared__ int lhist[NBUK];
  __shared__ int lbase[NBUK];
  __shared__ int gbase[NBUK];
  __shared__ int sm[256];
  __shared__ int2 sbuf[PCHUNK];
  __shared__ uint8_t bbuf[PCHUNK];
  int tid = threadIdx.x;
  int base = blockIdx.x * PCHUNK;
  int nE = N_EDGES - base;
  if (nE > PCHUNK) nE = PCHUNK;
  for (int t = tid; t < NBUK; t += 256) lhist[t] = 0;
  __syncthreads();
  bool i64 = (*flag != 0);
  int es[16], ed[16], ml[16];
  #pragma unroll
  for (int k = 0; k < 16; ++k) {
    int ci = k * 256 + tid;
    if (ci < nE) {
      int e = base + ci;
      int s, d;
      if (i64) {
        const uint32_t* u = (const uint32_t*)eidx;
        s = (int)u[2 * (size_t)e];
        d = (int)u[2 * ((size_t)N_EDGES + e)];
      } else {
        const int* u = (const int*)eidx;
        s = u[e];
        d = u[N_EDGES + e];
      }
      es[k] = s; ed[k] = d;
      ml[k] = atomicAdd(&lhist[d >> BSH], 1);
    }
  }
  __syncthreads();
  sm[tid] = (tid < NBUK) ? lhist[tid] : 0;
  __syncthreads();
  for (int s = 1; s < 256; s <<= 1) {
    int t = (tid >= s) ? sm[tid - s] : 0;
    __syncthreads();
    sm[tid] += t;
    __syncthreads();
  }
  if (tid < NBUK) lbase[tid] = sm[tid] - lhist[tid];
  __syncthreads();
  #pragma unroll
  for (int k = 0; k < 16; ++k) {
    int ci = k * 256 + tid;
    if (ci < nE) {
      int b = ed[k] >> BSH;
      int slot = lbase[b] + ml[k];
      sbuf[slot] = make_int2(es[k], ed[k]);
      bbuf[slot] = (uint8_t)b;
    }
  }
  if (tid < NBUK && lhist[tid] > 0) gbase[tid] = atomicAdd(&bcur[tid], lhist[tid]);
  __syncthreads();
  for (int i = tid; i < nE; i += 256) {
    int b = bbuf[i];
    part[(size_t)gbase[b] + (i - lbase[b])] = sbuf[i];
  }
}

// ---- bucketA: per-node exact counts + dinv + padded bucket totals ----
__global__ __launch_bounds__(256) void k_bucketA(const int2* __restrict__ part,
                                                 const int* __restrict__ bbase,
                                                 int* __restrict__ cntg,
                                                 float* __restrict__ dinv,
                                                 int* __restrict__ ptot) {
  __shared__ int cnt[512];
  __shared__ int s2[256];
  int tid = threadIdx.x, b = blockIdx.x;
  int v0 = b << BSH;
  int e0 = bbase[b], e1 = bbase[b + 1];
  cnt[tid] = 0; cnt[tid + 256] = 0;
  __syncthreads();
  for (int i = e0 + tid; i < e1; i += 256) atomicAdd(&cnt[part[i].y - v0], 1);
  __syncthreads();
  int pa = (cnt[2 * tid] + 3) & ~3, pb = (cnt[2 * tid + 1] + 3) & ~3;
  s2[tid] = pa + pb;
  __syncthreads();
  for (int s = 128; s > 0; s >>= 1) {
    if (tid < s) s2[tid] += s2[tid + s];
    __syncthreads();
  }
  if (tid == 0) ptot[b] = s2[0];
  #pragma unroll
  for (int k = 0; k < 2; ++k) {
    int t = tid + k * 256, v = v0 + t;
    if (v < N_NODES) {
      cntg[v] = cnt[t];
      dinv[v] = rsqrtf((float)(cnt[t] + 1));
    }
  }
}

// ---- serial padded-base scan ----
__global__ void k_bscan2(const int* __restrict__ ptot, int* __restrict__ pbase,
                         int* __restrict__ offs) {
  if (threadIdx.x == 0 && blockIdx.x == 0) {
    int run = 0;
    for (int b = 0; b < NBUK; ++b) { pbase[b] = run; run += ptot[b]; }
    pbase[NBUK] = run;
    offs[N_NODES] = run;
  }
}

// ---- bucketB: padded offs + scatter + sentinel pad fill ----
__global__ __launch_bounds__(256) void k_bucketB(const int2* __restrict__ part,
                                                 const int* __restrict__ bbase,
                                                 const int* __restrict__ pbase,
                                                 const int* __restrict__ cntg,
                                                 int* __restrict__ offs,
                                                 int* __restrict__ sedge) {
  __shared__ int pre[512];
  __shared__ int cur[512];
  __shared__ int s2[256];
  int tid = threadIdx.x, b = blockIdx.x;
  int v0 = b << BSH;
  int e0 = bbase[b], e1 = bbase[b + 1];
  int e0p = pbase[b];
  int c0 = (v0 + 2 * tid < N_NODES) ? cntg[v0 + 2 * tid] : 0;
  int c1 = (v0 + 2 * tid + 1 < N_NODES) ? cntg[v0 + 2 * tid + 1] : 0;
  int pa = (c0 + 3) & ~3, pb = (c1 + 3) & ~3;
  s2[tid] = pa + pb;
  __syncthreads();
  for (int s = 1; s < 256; s <<= 1) {
    int t = (tid >= s) ? s2[tid - s] : 0;
    __syncthreads();
    s2[tid] += t;
    __syncthreads();
  }
  int eb = s2[tid] - (pa + pb);
  pre[2 * tid] = eb;       cur[2 * tid] = eb;
  pre[2 * tid + 1] = eb + pa; cur[2 * tid + 1] = eb + pa;
  __syncthreads();
  #pragma unroll
  for (int k = 0; k < 2; ++k) {
    int t = tid + k * 256, v = v0 + t;
    if (v < N_NODES) offs[v] = e0p + pre[t];
  }
  for (int i = e0 + tid; i < e1; i += 256) {
    int2 e = part[i];
    int p = atomicAdd(&cur[e.y - v0], 1);
    sedge[e0p + p] = e.x;
  }
  __syncthreads();
  #pragma unroll
  for (int k = 0; k < 2; ++k) {
    int t = tid + k * 256, v = v0 + t;
    if (v < N_NODES) {
      int endx = cur[t];
      int endp = pre[t] + ((endx - pre[t] + 3) & ~3);
      for (int u = endx; u < endp; ++u) sedge[e0p + u] = N_NODES;  // sentinel row
    }
  }
}

// pack W [K][HID] f32 row-major into MFMA B-fragment-ready bf16 layout
__global__ void k_packW(const float* __restrict__ W, uint16_t* __restrict__ Wp, int K) {
  int t = blockIdx.x * blockDim.x + threadIdx.x;
  int total = (K / 32) * 8 * 64;
  if (t >= total) return;
  int l = t & 63;
  int nt = (t >> 6) & 7;
  int ks = t >> 9;
  int kbase = ks * 32 + (l >> 4) * 8;
  int col = nt * 16 + (l & 15);
  #pragma unroll
  for (int j = 0; j < 8; ++j)
    Wp[(size_t)t * 8 + j] = (uint16_t)f2bf(W[(size_t)(kbase + j) * HID + col]);
}

// epilogue: store h' = dinv[row] * acc as fp8 e4m3 rows, via swizzled LDS repack
__device__ __forceinline__ void epilogue_fp8(const f32x4* acc, int l, int row0,
                                             uint8_t* lds_my,
                                             uint8_t* __restrict__ H8,
                                             const float* __restrict__ dinv) {
  float dv[4];
  #pragma unroll
  for (int j = 0; j < 4; ++j) {
    int r = row0 + (l >> 4) * 4 + j;
    dv[j] = dinv[min(r, N_NODES - 1)];
  }
  #pragma unroll
  for (int nt = 0; nt < 8; ++nt)
    #pragma unroll
    for (int j = 0; j < 4; ++j) {
      int r = (l >> 4) * 4 + j, c = nt * 16 + (l & 15);
      uint32_t pk = __builtin_amdgcn_cvt_pk_fp8_f32(acc[nt][j] * dv[j], 0.f, 0u, false);
      lds_my[r * 128 + (c ^ ((r & 7) << 2))] = (uint8_t)pk;  // 4B-granule swizzle by row
    }
  asm volatile("s_waitcnt lgkmcnt(0)" ::: "memory");
  int r = l >> 2;
  uint32_t w[8];
  #pragma unroll
  for (int t = 0; t < 8; ++t) {
    int c4 = (l & 3) * 8 + t;
    w[t] = *(const uint32_t*)(lds_my + r * 128 + ((c4 ^ (r & 7)) << 2));
  }
  if (row0 + r < N_NODES) {
    uint4* gp = (uint4*)(H8 + (size_t)(row0 + r) * 128 + (l & 3) * 32);
    gp[0] = make_uint4(w[0], w[1], w[2], w[3]);
    gp[1] = make_uint4(w[4], w[5], w[6], w[7]);
  }
  asm volatile("s_waitcnt lgkmcnt(0)" ::: "memory");
}

// layer-0 fused dual GEMM in one launch: blocks [0,782) do X@W0 -> fp8 h';
// blocks [782,1564) do X@Wr -> bf16 residual. f32 A read + in-flight cvt.
__global__ __launch_bounds__(256) void k_gemm0d(const float* __restrict__ X,
                                                const uint16_t* __restrict__ Wp0,
                                                const uint16_t* __restrict__ WpR,
                                                uint8_t* __restrict__ H8,
                                                const float* __restrict__ dinv,
                                                uint16_t* __restrict__ resB) {
  __shared__ __align__(16) char smem[32768];
  int tid = threadIdx.x, wid = tid >> 6, l = tid & 63;
  bool second = blockIdx.x >= GEMM_GRID;
  int blk = second ? (blockIdx.x - GEMM_GRID) : blockIdx.x;
  const uint16_t* Wp = second ? WpR : Wp0;
  int r0 = blk * 128 + wid * 32;
  int hk = l >> 4, rl = l & 15;
  int ra0 = min(r0 + rl, N_NODES - 1);
  int ra1 = min(r0 + 16 + rl, N_NODES - 1);
  f32x4 acc[2][8] = {};
  #pragma unroll
  for (int kh = 0; kh < 2; ++kh) {
    __syncthreads();
    #pragma unroll
    for (int i = 0; i < 8; ++i) {
      int gidx = i * 256 + tid;
      *(uint4*)(smem + gidx * 16) =
          *(const uint4*)((const char*)Wp + (size_t)kh * 32768 + gidx * 16);
    }
    __syncthreads();
    #pragma unroll
    for (int ksl = 0; ksl < 4; ++ksl) {
      int kof = kh * 128 + ksl * 32 + hk * 8;
      float4 u0 = *(const float4*)(X + (size_t)ra0 * 256 + kof);
      float4 u1 = *(const float4*)(X + (size_t)ra0 * 256 + kof + 4);
      float4 w0 = *(const float4*)(X + (size_t)ra1 * 256 + kof);
      float4 w1 = *(const float4*)(X + (size_t)ra1 * 256 + kof + 4);
      bf16x8 a0, a1;
      a0[0] = (short)f2bf(u0.x); a0[1] = (short)f2bf(u0.y);
      a0[2] = (short)f2bf(u0.z); a0[3] = (short)f2bf(u0.w);
      a0[4] = (short)f2bf(u1.x); a0[5] = (short)f2bf(u1.y);
      a0[6] = (short)f2bf(u1.z); a0[7] = (short)f2bf(u1.w);
      a1[0] = (short)f2bf(w0.x); a1[1] = (short)f2bf(w0.y);
      a1[2] = (short)f2bf(w0.z); a1[3] = (short)f2bf(w0.w);
      a1[4] = (short)f2bf(w1.x); a1[5] = (short)f2bf(w1.y);
      a1[6] = (short)f2bf(w1.z); a1[7] = (short)f2bf(w1.w);
      #pragma unroll
      for (int nt = 0; nt < 8; ++nt) {
        bf16x8 b = *(const bf16x8*)(smem + ((ksl * 8 + nt) * 64 + l) * 16);
        acc[0][nt] = __builtin_amdgcn_mfma_f32_16x16x32_bf16(a0, b, acc[0][nt], 0, 0, 0);
        acc[1][nt] = __builtin_amdgcn_mfma_f32_16x16x32_bf16(a1, b, acc[1][nt], 0, 0, 0);
      }
    }
  }
  __syncthreads();  // B dead; per-wave epilogue scratch (8KB each)
  if (!second) {
    uint8_t* lds8 = (uint8_t*)(smem + wid * 8192);
    epilogue_fp8(acc[0], l, r0, lds8, H8, dinv);
    epilogue_fp8(acc[1], l, r0 + 16, lds8, H8, dinv);
  } else {
    uint16_t* ldsb = (uint16_t*)(smem + wid * 8192);
    #pragma unroll
    for (int rt = 0; rt < 2; ++rt) {
      int row0 = r0 + rt * 16;
      #pragma unroll
      for (int nt = 0; nt < 8; ++nt)
        #pragma unroll
        for (int j = 0; j < 4; ++j)
          ldsb[((l >> 4) * 4 + j) * 128 + nt * 16 + (l & 15)] = (uint16_t)f2bf(acc[rt][nt][j]);
      asm volatile("s_waitcnt lgkmcnt(0)" ::: "memory");
      const uint4* sb = (const uint4*)ldsb;
      if (row0 + (l >> 2) < N_NODES) {
        uint4* gb = (uint4*)(resB + (size_t)(row0 + (l >> 2)) * 128 + (l & 3) * 32);
        #pragma unroll
        for (int t = 0; t < 4; ++t) gb[t] = sb[l * 4 + t];
      }
      asm volatile("s_waitcnt lgkmcnt(0)" ::: "memory");
    }
  }
}

// layers 1/2 GEMM: A bf16 [N][128] @ Wp(LDS-shared) -> fp8 h'
__global__ __launch_bounds__(256) void k_gemm8(const uint16_t* __restrict__ A,
                                               const uint16_t* __restrict__ Wp,
                                               uint8_t* __restrict__ H8,
                                               const float* __restrict__ dinv) {
  __shared__ __align__(16) char smem[32768];
  int tid = threadIdx.x, wid = tid >> 6, l = tid & 63;
  #pragma unroll
  for (int i = 0; i < 8; ++i) {
    int gidx = i * 256 + tid;
    *(uint4*)(smem + gidx * 16) = *(const uint4*)((const char*)Wp + gidx * 16);
  }
  __syncthreads();
  int r0 = blockIdx.x * 128 + wid * 32;
  int hk = l >> 4, rl = l & 15;
  int ra0 = min(r0 + rl, N_NODES - 1);
  int ra1 = min(r0 + 16 + rl, N_NODES - 1);
  f32x4 acc[2][8] = {};
  #pragma unroll
  for (int ks = 0; ks < 4; ++ks) {
    bf16x8 a0 = *(const bf16x8*)(A + (size_t)ra0 * 128 + ks * 32 + hk * 8);
    bf16x8 a1 = *(const bf16x8*)(A + (size_t)ra1 * 128 + ks * 32 + hk * 8);
    #pragma unroll
    for (int nt = 0; nt < 8; ++nt) {
      bf16x8 b = *(const bf16x8*)(smem + ((ks * 8 + nt) * 64 + l) * 16);
      acc[0][nt] = __builtin_amdgcn_mfma_f32_16x16x32_bf16(a0, b, acc[0][nt], 0, 0, 0);
      acc[1][nt] = __builtin_amdgcn_mfma_f32_16x16x32_bf16(a1, b, acc[1][nt], 0, 0, 0);
    }
  }
  __syncthreads();  // B dead; reuse as epilogue scratch
  uint8_t* lds8 = (uint8_t*)(smem + wid * 4096);
  epilogue_fp8(acc[0], l, r0, lds8, H8, dinv);
  epilogue_fp8(acc[1], l, r0 + 16, lds8, H8, dinv);
}

// fused: fp8 gather-sum + bias + LN + ReLU + bf16 residual
// four 16-lane quarters; quarter q owns 4-edge blocks jb%4==q (uint4 index loads);
// lane owns 8 channels (uint2 gather); unweighted fp8 row sum (scales pre-folded).
#define PROC(hx, hy)                                                   \
  do {                                                                 \
    f32x2 f_;                                                          \
    f_ = __builtin_amdgcn_cvt_pk_f32_fp8((hx), false);                 \
    asm("v_pk_add_f32 %0, %0, %1" : "+v"(A01) : "v"(f_));              \
    f_ = __builtin_amdgcn_cvt_pk_f32_fp8((hx), true);                  \
    asm("v_pk_add_f32 %0, %0, %1" : "+v"(A23) : "v"(f_));              \
    f_ = __builtin_amdgcn_cvt_pk_f32_fp8((hy), false);                 \
    asm("v_pk_add_f32 %0, %0, %1" : "+v"(A45) : "v"(f_));              \
    f_ = __builtin_amdgcn_cvt_pk_f32_fp8((hy), true);                  \
    asm("v_pk_add_f32 %0, %0, %1" : "+v"(A67) : "v"(f_));              \
  } while (0)

__global__ __launch_bounds__(256) void k_agg(const uint8_t* __restrict__ H8,
                                             const int* __restrict__ sedge,
                                             const int* __restrict__ offs,
                                             const float* __restrict__ dinv,
                                             const float* __restrict__ bias,
                                             const float* __restrict__ g,
                                             const float* __restrict__ be,
                                             const uint16_t* __restrict__ residB,
                                             float* __restrict__ outF,
                                             uint16_t* __restrict__ outB) {
  int wid = threadIdx.x >> 6, l = threadIdx.x & 63;
  int v = blockIdx.x * 4 + wid;
  if (v >= N_NODES) return;
  int q = l >> 4, c = l & 15;
  uint32_t coff = (uint32_t)c << 3;
  f32x2 A01 = {0.f, 0.f}, A23 = {0.f, 0.f}, A45 = {0.f, 0.f}, A67 = {0.f, 0.f};
  int p0 = offs[v];
  int nb = (offs[v + 1] - p0) >> 2;      // 4-edge blocks (padded, exact)
  const uint4* sblk = (const uint4*)(sedge + p0);
  int jb = q;
  for (; jb + 4 < nb; jb += 8) {
    uint4 i0 = sblk[jb];
    uint4 i1 = sblk[jb + 4];
    uint2 h0 = *(const uint2*)(H8 + ((i0.x << 7) | coff));
    uint2 h1 = *(const uint2*)(H8 + ((i0.y << 7) | coff));
    uint2 h2 = *(const uint2*)(H8 + ((i0.z << 7) | coff));
    uint2 h3 = *(const uint2*)(H8 + ((i0.w << 7) | coff));
    uint2 h4 = *(const uint2*)(H8 + ((i1.x << 7) | coff));
    uint2 h5 = *(const uint2*)(H8 + ((i1.y << 7) | coff));
    uint2 h6 = *(const uint2*)(H8 + ((i1.z << 7) | coff));
    uint2 h7 = *(const uint2*)(H8 + ((i1.w << 7) | coff));
    PROC(h0.x, h0.y); PROC(h1.x, h1.y); PROC(h2.x, h2.y); PROC(h3.x, h3.y);
    PROC(h4.x, h4.y); PROC(h5.x, h5.y); PROC(h6.x, h6.y); PROC(h7.x, h7.y);
  }
  for (; jb < nb; jb += 4) {
    uint4 i0 = sblk[jb];
    uint2 h0 = *(const uint2*)(H8 + ((i0.x << 7) | coff));
    uint2 h1 = *(const uint2*)(H8 + ((i0.y << 7) | coff));
    uint2 h2 = *(const uint2*)(H8 + ((i0.z << 7) | coff));
    uint2 h3 = *(const uint2*)(H8 + ((i0.w << 7) | coff));
    PROC(h0.x, h0.y); PROC(h1.x, h1.y); PROC(h2.x, h2.y); PROC(h3.x, h3.y);
  }
  if (q == 0) {  // self loop: + own h' row
    uint2 h = *(const uint2*)(H8 + (((uint32_t)v << 7) | coff));
    PROC(h.x, h.y);
  }
  // combine the 4 quarters
  float a0 = A01.x, a1 = A01.y, a2 = A23.x, a3 = A23.y;
  float a4 = A45.x, a5 = A45.y, a6 = A67.x, a7 = A67.y;
  #pragma unroll
  for (int m = 16; m <= 32; m <<= 1) {
    a0 += __shfl_xor(a0, m, 64); a1 += __shfl_xor(a1, m, 64);
    a2 += __shfl_xor(a2, m, 64); a3 += __shfl_xor(a3, m, 64);
    a4 += __shfl_xor(a4, m, 64); a5 += __shfl_xor(a5, m, 64);
    a6 += __shfl_xor(a6, m, 64); a7 += __shfl_xor(a7, m, 64);
  }
  float dv = dinv[v];
  float4 bb0 = *(const float4*)(bias + 8 * c);
  float4 bb1 = *(const float4*)(bias + 8 * c + 4);
  a0 = dv * a0 + bb0.x; a1 = dv * a1 + bb0.y;
  a2 = dv * a2 + bb0.z; a3 = dv * a3 + bb0.w;
  a4 = dv * a4 + bb1.x; a5 = dv * a5 + bb1.y;
  a6 = dv * a6 + bb1.z; a7 = dv * a7 + bb1.w;
  // LayerNorm over 128 channels (16-lane reduction, replicated across quarters)
  float s = a0 + a1 + a2 + a3 + a4 + a5 + a6 + a7;
  #pragma unroll
  for (int m = 1; m < 16; m <<= 1) s += __shfl_xor(s, m, 64);
  float mu = s * (1.f / 128.f);
  float d0 = a0 - mu, d1 = a1 - mu, d2 = a2 - mu, d3 = a3 - mu;
  float d4 = a4 - mu, d5 = a5 - mu, d6 = a6 - mu, d7 = a7 - mu;
  float qq = d0 * d0 + d1 * d1 + d2 * d2 + d3 * d3 +
             d4 * d4 + d5 * d5 + d6 * d6 + d7 * d7;
  #pragma unroll
  for (int m = 1; m < 16; m <<= 1) qq += __shfl_xor(qq, m, 64);
  float rs = rsqrtf(qq * (1.f / 128.f) + EPS);
  float4 gg0 = *(const float4*)(g + 8 * c);
  float4 gg1 = *(const float4*)(g + 8 * c + 4);
  float4 ee0 = *(const float4*)(be + 8 * c);
  float4 ee1 = *(const float4*)(be + 8 * c + 4);
  float y0 = fmaxf(d0 * rs * gg0.x + ee0.x, 0.f);
  float y1 = fmaxf(d1 * rs * gg0.y + ee0.y, 0.f);
  float y2 = fmaxf(d2 * rs * gg0.z + ee0.z, 0.f);
  float y3 = fmaxf(d3 * rs * gg0.w + ee0.w, 0.f);
  float y4 = fmaxf(d4 * rs * gg1.x + ee1.x, 0.f);
  float y5 = fmaxf(d5 * rs * gg1.y + ee1.y, 0.f);
  float y6 = fmaxf(d6 * rs * gg1.z + ee1.z, 0.f);
  float y7 = fmaxf(d7 * rs * gg1.w + ee1.w, 0.f);
  uint4 rr = *(const uint4*)(residB + (size_t)v * 128 + 8 * c);
  y0 += bflo(rr.x); y1 += bfhi(rr.x);
  y2 += bflo(rr.y); y3 += bfhi(rr.y);
  y4 += bflo(rr.z); y5 += bfhi(rr.z);
  y6 += bflo(rr.w); y7 += bfhi(rr.w);
  if (q == 0) {
    if (outF) {
      float* op = outF + (size_t)v * HID + 8 * c;
      *(float4*)op = make_float4(y0, y1, y2, y3);
      *(float4*)(op + 4) = make_float4(y4, y5, y6, y7);
    }
    if (outB) {
      uint4 o;
      o.x = f2bf(y0) | (f2bf(y1) << 16);
      o.y = f2bf(y2) | (f2bf(y3) << 16);
      o.z = f2bf(y4) | (f2bf(y5) << 16);
      o.w = f2bf(y6) | (f2bf(y7) << 16);
      *(uint4*)(outB + (size_t)v * 128 + 8 * c) = o;
    }
  }
}

extern "C" void kernel_launch(void* const* d_in, const int* in_sizes, int n_in,
                              void* d_out, int out_size, void* d_ws, size_t ws_size,
                              hipStream_t stream) {
  const float* x   = (const float*)d_in[0];
  const void*  ei  = d_in[1];
  const float* W0  = (const float*)d_in[2];
  const float* b0  = (const float*)d_in[3];
  const float* g0  = (const float*)d_in[4];
  const float* be0 = (const float*)d_in[5];
  const float* W1  = (const float*)d_in[6];
  const float* b1  = (const float*)d_in[7];
  const float* g1  = (const float*)d_in[8];
  const float* be1 = (const float*)d_in[9];
  const float* W2  = (const float*)d_in[10];
  const float* b2  = (const float*)d_in[11];
  const float* g2  = (const float*)d_in[12];
  const float* be2 = (const float*)d_in[13];
  const float* Wr  = (const float*)d_in[14];

  char* ws = (char*)d_ws;
  int*      sedge  = (int*)(ws + OFF_SRC);
  int*      offs   = (int*)(ws + OFF_OFFS);
  float*    dinv   = (float*)(ws + OFF_DINV);
  int*      cntg   = (int*)(ws + OFF_CNTG);
  uint16_t* wpk0   = (uint16_t*)(ws + OFF_WPK0);
  uint16_t* wpk1   = (uint16_t*)(ws + OFF_WPK1);
  uint16_t* wpk2   = (uint16_t*)(ws + OFF_WPK2);
  uint16_t* wpkr   = (uint16_t*)(ws + OFF_WPKR);
  int*      flag   = (int*)(ws + OFF_FLAG);
  int*      bcnt   = (int*)(ws + OFF_BCNT);
  int*      bbase  = (int*)(ws + OFF_BBASE);
  int*      bcur   = (int*)(ws + OFF_BCUR);
  int*      ptot   = (int*)(ws + OFF_PTOT);
  int*      pbase  = (int*)(ws + OFF_PBASE);
  uint8_t*  h8     = (uint8_t*)(ws + OFF_H8);
  int2*     part   = (int2*)(ws + OFF_PART);
  uint16_t* resB   = (uint16_t*)(ws + OFF_RESB);
  uint16_t* hbA    = (uint16_t*)(ws + OFF_HBA);
  uint16_t* hbB    = (uint16_t*)(ws + OFF_HBB);
  float*    out    = (float*)d_out;

  // ---- edge preprocessing: hist -> scan -> partition -> padded per-bucket CSR ----
  k_flag<<<1, 256, 0, stream>>>((const uint32_t*)ei, flag);
  hipMemsetAsync(bcnt, 0, NBUK * sizeof(int), stream);
  k_hist<<<2048, 256, 0, stream>>>(ei, flag, bcnt);
  k_bscan<<<1, 64, 0, stream>>>(bcnt, bbase, bcur);
  k_part<<<(N_EDGES + PCHUNK - 1) / PCHUNK, 256, 0, stream>>>(ei, flag, bcur, part);
  k_bucketA<<<NBUK, 256, 0, stream>>>(part, bbase, cntg, dinv, ptot);
  k_bscan2<<<1, 64, 0, stream>>>(ptot, pbase, offs);
  k_bucketB<<<NBUK, 256, 0, stream>>>(part, bbase, pbase, cntg, offs, sedge);
  // sentinel row (src == N_NODES) must be zero; part buffer is dead now
  hipMemsetAsync(h8 + (size_t)N_NODES * 128, 0, 128, stream);

  // ---- weight packing ----
  k_packW<<<16, 256, 0, stream>>>(W0, wpk0, IN_CH);
  k_packW<<<8, 256, 0, stream>>>(W1, wpk1, HID);
  k_packW<<<8, 256, 0, stream>>>(W2, wpk2, HID);
  k_packW<<<16, 256, 0, stream>>>(Wr, wpkr, IN_CH);

  // ---- layer 0: fused dual K=256 GEMM launch (x@W0 -> fp8 h', x@Wr -> bf16 resid) ----
  k_gemm0d<<<2 * GEMM_GRID, 256, 0, stream>>>(x, wpk0, wpkr, h8, dinv, resB);
  k_agg<<<25000, 256, 0, stream>>>(h8, sedge, offs, dinv, b0, g0, be0, resB, nullptr, hbA);

  // ---- layer 1 ----
  k_gemm8<<<GEMM_GRID, 256, 0, stream>>>(hbA, wpk1, h8, dinv);
  k_agg<<<25000, 256, 0, stream>>>(h8, sedge, offs, dinv, b1, g1, be1, hbA, nullptr, hbB);

  // ---- layer 2 (writes d_out f32) ----
  k_gemm8<<<GEMM_GRID, 256, 0, stream>>>(hbB, wpk2, h8, dinv);
  k_agg<<<25000, 256, 0, stream>>>(h8, sedge, offs, dinv, b2, g2, be2, hbB, out, nullptr);

  (void)in_sizes; (void)n_in; (void)out_size; (void)ws_size;
}

// Round 12
// 393.835 us; speedup vs baseline: 2.0678x; 1.1496x over previous
//
#include <hip/hip_runtime.h>
#include <hip/hip_bf16.h>
#include <stdint.h>

#define N_NODES 100000
#define N_EDGES 3200000
#define IN_CH 256
#define HID 128
#define EPS 1e-5f
#define BSH 9              // bucket = dst >> 9  (512 nodes per bucket)
#define NBUK 196           // ceil(100000/512)
#define PCAP 17664         // fixed bucket capacity (mean 16327, +10 sigma)
#define PCHUNK 4096
#define GEMM_GRID 782      // ceil(100000/128)

using bf16x8 = __attribute__((ext_vector_type(8))) short;
using f32x4  = __attribute__((ext_vector_type(4))) float;
using f32x2  = __attribute__((ext_vector_type(2))) float;

__device__ __forceinline__ uint32_t f2bf(float f) {
  uint32_t u = __float_as_uint(f);
  return (u + 0x7FFFu + ((u >> 16) & 1u)) >> 16;
}
__device__ __forceinline__ float bflo(uint32_t u) { return __uint_as_float(u << 16); }
__device__ __forceinline__ float bfhi(uint32_t u) { return __uint_as_float(u & 0xFFFF0000u); }

// ---- workspace layout (bytes) ----
static const size_t OFF_SRC   = 0;            // int[196*17664] padded CSR = 13,848,576
static const size_t OFF_OFFS2 = 13848576;     // int2[100000] = 800,000
static const size_t OFF_DINV  = 14648576;     // float[100000]
static const size_t OFF_WPK0  = 15048576;     // 65,536
static const size_t OFF_WPK1  = 15114112;     // 32,768
static const size_t OFF_WPK2  = 15146880;     // 32,768
static const size_t OFF_WPKR  = 15179648;     // 65,536
static const size_t OFF_FLAG  = 15245184;     // int (+pad)
static const size_t OFF_BCUR  = 15245312;     // int[NBUK] (+pad)
static const size_t OFF_H8    = 15246336;     // fp8[100001*128] = 12,800,128
static const size_t OFF_PART  = 15246336;     // int2[196*17664] = 27,697,152 (aliases H8; dead before GEMM)
static const size_t OFF_RESB  = 42943616;     // bf16[100000*128] = 25,600,000
static const size_t OFF_HBA   = 68543616;     // bf16[100000*128]
static const size_t OFF_HBB   = 94143616;     // bf16[100000*128]  (end ~119.7MB)

// ---- edge dtype detection: int64 edges have zero high words ----
__global__ void k_flag(const uint32_t* __restrict__ e, int* flag) {
  __shared__ int any;
  if (threadIdx.x == 0) any = 0;
  __syncthreads();
  uint32_t acc = 0;
  for (int i = threadIdx.x; i < 2048; i += blockDim.x) acc |= e[2 * i + 1];
  if (acc) atomicOr(&any, 1);
  __syncthreads();
  if (threadIdx.x == 0) *flag = (any == 0) ? 1 : 0;  // 1 => int64 layout
}

// ---- init static bucket cursors ----
__global__ void k_init(int* __restrict__ bcur) {
  int t = threadIdx.x;
  if (t < NBUK) bcur[t] = t * PCAP;
}

// ---- LDS-staged partition into fixed-capacity buckets (coalesced writes) ----
__global__ __launch_bounds__(256) void k_part(const void* __restrict__ eidx,
                                              const int* __restrict__ flag,
                                              int* __restrict__ bcur,
                                              int2* __restrict__ part) {
  __shared__ int lhist[NBUK];
  __shared__ int lbase[NBUK];
  __shared__ int gbase[NBUK];
  __shared__ int sm[256];
  __shared__ int2 sbuf[PCHUNK];
  __shared__ uint8_t bbuf[PCHUNK];
  int tid = threadIdx.x;
  int base = blockIdx.x * PCHUNK;
  int nE = N_EDGES - base;
  if (nE > PCHUNK) nE = PCHUNK;
  for (int t = tid; t < NBUK; t += 256) lhist[t] = 0;
  __syncthreads();
  bool i64 = (*flag != 0);
  int es[16], ed[16], ml[16];
  #pragma unroll
  for (int k = 0; k < 16; ++k) {
    int ci = k * 256 + tid;
    if (ci < nE) {
      int e = base + ci;
      int s, d;
      if (i64) {
        const uint32_t* u = (const uint32_t*)eidx;
        s = (int)u[2 * (size_t)e];
        d = (int)u[2 * ((size_t)N_EDGES + e)];
      } else {
        const int* u = (const int*)eidx;
        s = u[e];
        d = u[N_EDGES + e];
      }
      es[k] = s; ed[k] = d;
      ml[k] = atomicAdd(&lhist[d >> BSH], 1);
    }
  }
  __syncthreads();
  sm[tid] = (tid < NBUK) ? lhist[tid] : 0;
  __syncthreads();
  for (int s = 1; s < 256; s <<= 1) {
    int t = (tid >= s) ? sm[tid - s] : 0;
    __syncthreads();
    sm[tid] += t;
    __syncthreads();
  }
  if (tid < NBUK) lbase[tid] = sm[tid] - lhist[tid];
  __syncthreads();
  #pragma unroll
  for (int k = 0; k < 16; ++k) {
    int ci = k * 256 + tid;
    if (ci < nE) {
      int b = ed[k] >> BSH;
      int slot = lbase[b] + ml[k];
      sbuf[slot] = make_int2(es[k], ed[k]);
      bbuf[slot] = (uint8_t)b;
    }
  }
  if (tid < NBUK && lhist[tid] > 0) gbase[tid] = atomicAdd(&bcur[tid], lhist[tid]);
  __syncthreads();
  for (int i = tid; i < nE; i += 256) {
    int b = bbuf[i];
    part[(size_t)gbase[b] + (i - lbase[b])] = sbuf[i];
  }
}

// ---- fused bucket pass: count -> padded scan -> offs2/dinv -> scatter -> pad fill ----
__global__ __launch_bounds__(256) void k_bucket(const int2* __restrict__ part,
                                                const int* __restrict__ bcur,
                                                int2* __restrict__ offs2,
                                                float* __restrict__ dinv,
                                                int* __restrict__ sedge) {
  __shared__ int cnt[512];
  __shared__ int pre[512];
  __shared__ int cur[512];
  __shared__ int s2[256];
  int tid = threadIdx.x, b = blockIdx.x;
  int v0 = b << BSH;
  int e0 = b * PCAP;
  int e1 = bcur[b];                     // final cursor == e0 + bucket count
  cnt[tid] = 0; cnt[tid + 256] = 0;
  __syncthreads();
  for (int i = e0 + tid; i < e1; i += 256) atomicAdd(&cnt[part[i].y - v0], 1);
  __syncthreads();
  int pa = (cnt[2 * tid] + 3) & ~3, pb = (cnt[2 * tid + 1] + 3) & ~3;
  s2[tid] = pa + pb;
  __syncthreads();
  for (int s = 1; s < 256; s <<= 1) {
    int t = (tid >= s) ? s2[tid - s] : 0;
    __syncthreads();
    s2[tid] += t;
    __syncthreads();
  }
  int eb = s2[tid] - (pa + pb);
  pre[2 * tid] = eb;          cur[2 * tid] = eb;
  pre[2 * tid + 1] = eb + pa; cur[2 * tid + 1] = eb + pa;
  __syncthreads();
  #pragma unroll
  for (int k = 0; k < 2; ++k) {
    int t = tid + k * 256, v = v0 + t;
    if (v < N_NODES) {
      int c = cnt[t];
      offs2[v] = make_int2(e0 + pre[t], ((c + 3) & ~3) >> 2);
      dinv[v] = rsqrtf((float)(c + 1));
    }
  }
  __syncthreads();
  for (int i = e0 + tid; i < e1; i += 256) {
    int2 e = part[i];
    int p = atomicAdd(&cur[e.y - v0], 1);
    sedge[e0 + p] = e.x;
  }
  __syncthreads();
  #pragma unroll
  for (int k = 0; k < 2; ++k) {
    int t = tid + k * 256, v = v0 + t;
    if (v < N_NODES) {
      int endx = cur[t];
      int endp = pre[t] + ((endx - pre[t] + 3) & ~3);
      for (int u = endx; u < endp; ++u) sedge[e0 + u] = N_NODES;  // sentinel row
    }
  }
}

// pack W [K][HID] f32 row-major into MFMA B-fragment-ready bf16 layout
__global__ void k_packW(const float* __restrict__ W, uint16_t* __restrict__ Wp, int K) {
  int t = blockIdx.x * blockDim.x + threadIdx.x;
  int total = (K / 32) * 8 * 64;
  if (t >= total) return;
  int l = t & 63;
  int nt = (t >> 6) & 7;
  int ks = t >> 9;
  int kbase = ks * 32 + (l >> 4) * 8;
  int col = nt * 16 + (l & 15);
  #pragma unroll
  for (int j = 0; j < 8; ++j)
    Wp[(size_t)t * 8 + j] = (uint16_t)f2bf(W[(size_t)(kbase + j) * HID + col]);
}

// epilogue: store h' = dinv[row] * acc as fp8 e4m3 rows, via swizzled LDS repack
__device__ __forceinline__ void epilogue_fp8(const f32x4* acc, int l, int row0,
                                             uint8_t* lds_my,
                                             uint8_t* __restrict__ H8,
                                             const float* __restrict__ dinv) {
  float dv[4];
  #pragma unroll
  for (int j = 0; j < 4; ++j) {
    int r = row0 + (l >> 4) * 4 + j;
    dv[j] = dinv[min(r, N_NODES - 1)];
  }
  #pragma unroll
  for (int nt = 0; nt < 8; ++nt)
    #pragma unroll
    for (int j = 0; j < 4; ++j) {
      int r = (l >> 4) * 4 + j, c = nt * 16 + (l & 15);
      uint32_t pk = __builtin_amdgcn_cvt_pk_fp8_f32(acc[nt][j] * dv[j], 0.f, 0u, false);
      lds_my[r * 128 + (c ^ ((r & 7) << 2))] = (uint8_t)pk;  // 4B-granule swizzle by row
    }
  asm volatile("s_waitcnt lgkmcnt(0)" ::: "memory");
  int r = l >> 2;
  uint32_t w[8];
  #pragma unroll
  for (int t = 0; t < 8; ++t) {
    int c4 = (l & 3) * 8 + t;
    w[t] = *(const uint32_t*)(lds_my + r * 128 + ((c4 ^ (r & 7)) << 2));
  }
  if (row0 + r < N_NODES) {
    uint4* gp = (uint4*)(H8 + (size_t)(row0 + r) * 128 + (l & 3) * 32);
    gp[0] = make_uint4(w[0], w[1], w[2], w[3]);
    gp[1] = make_uint4(w[4], w[5], w[6], w[7]);
  }
  asm volatile("s_waitcnt lgkmcnt(0)" ::: "memory");
}

// layer-0 fused dual GEMM in one launch: blocks [0,782) do X@W0 -> fp8 h';
// blocks [782,1564) do X@Wr -> bf16 residual. f32 A read + in-flight cvt.
__global__ __launch_bounds__(256) void k_gemm0d(const float* __restrict__ X,
                                                const uint16_t* __restrict__ Wp0,
                                                const uint16_t* __restrict__ WpR,
                                                uint8_t* __restrict__ H8,
                                                const float* __restrict__ dinv,
                                                uint16_t* __restrict__ resB) {
  __shared__ __align__(16) char smem[32768];
  int tid = threadIdx.x, wid = tid >> 6, l = tid & 63;
  bool second = blockIdx.x >= GEMM_GRID;
  int blk = second ? (blockIdx.x - GEMM_GRID) : blockIdx.x;
  const uint16_t* Wp = second ? WpR : Wp0;
  int r0 = blk * 128 + wid * 32;
  int hk = l >> 4, rl = l & 15;
  int ra0 = min(r0 + rl, N_NODES - 1);
  int ra1 = min(r0 + 16 + rl, N_NODES - 1);
  f32x4 acc[2][8] = {};
  #pragma unroll
  for (int kh = 0; kh < 2; ++kh) {
    __syncthreads();
    #pragma unroll
    for (int i = 0; i < 8; ++i) {
      int gidx = i * 256 + tid;
      *(uint4*)(smem + gidx * 16) =
          *(const uint4*)((const char*)Wp + (size_t)kh * 32768 + gidx * 16);
    }
    __syncthreads();
    #pragma unroll
    for (int ksl = 0; ksl < 4; ++ksl) {
      int kof = kh * 128 + ksl * 32 + hk * 8;
      float4 u0 = *(const float4*)(X + (size_t)ra0 * 256 + kof);
      float4 u1 = *(const float4*)(X + (size_t)ra0 * 256 + kof + 4);
      float4 w0 = *(const float4*)(X + (size_t)ra1 * 256 + kof);
      float4 w1 = *(const float4*)(X + (size_t)ra1 * 256 + kof + 4);
      bf16x8 a0, a1;
      a0[0] = (short)f2bf(u0.x); a0[1] = (short)f2bf(u0.y);
      a0[2] = (short)f2bf(u0.z); a0[3] = (short)f2bf(u0.w);
      a0[4] = (short)f2bf(u1.x); a0[5] = (short)f2bf(u1.y);
      a0[6] = (short)f2bf(u1.z); a0[7] = (short)f2bf(u1.w);
      a1[0] = (short)f2bf(w0.x); a1[1] = (short)f2bf(w0.y);
      a1[2] = (short)f2bf(w0.z); a1[3] = (short)f2bf(w0.w);
      a1[4] = (short)f2bf(w1.x); a1[5] = (short)f2bf(w1.y);
      a1[6] = (short)f2bf(w1.z); a1[7] = (short)f2bf(w1.w);
      #pragma unroll
      for (int nt = 0; nt < 8; ++nt) {
        bf16x8 b = *(const bf16x8*)(smem + ((ksl * 8 + nt) * 64 + l) * 16);
        acc[0][nt] = __builtin_amdgcn_mfma_f32_16x16x32_bf16(a0, b, acc[0][nt], 0, 0, 0);
        acc[1][nt] = __builtin_amdgcn_mfma_f32_16x16x32_bf16(a1, b, acc[1][nt], 0, 0, 0);
      }
    }
  }
  __syncthreads();  // B dead; per-wave epilogue scratch (8KB each)
  if (!second) {
    uint8_t* lds8 = (uint8_t*)(smem + wid * 8192);
    epilogue_fp8(acc[0], l, r0, lds8, H8, dinv);
    epilogue_fp8(acc[1], l, r0 + 16, lds8, H8, dinv);
  } else {
    uint16_t* ldsb = (uint16_t*)(smem + wid * 8192);
    #pragma unroll
    for (int rt = 0; rt < 2; ++rt) {
      int row0 = r0 + rt * 16;
      #pragma unroll
      for (int nt = 0; nt < 8; ++nt)
        #pragma unroll
        for (int j = 0; j < 4; ++j)
          ldsb[((l >> 4) * 4 + j) * 128 + nt * 16 + (l & 15)] = (uint16_t)f2bf(acc[rt][nt][j]);
      asm volatile("s_waitcnt lgkmcnt(0)" ::: "memory");
      const uint4* sb = (const uint4*)ldsb;
      if (row0 + (l >> 2) < N_NODES) {
        uint4* gb = (uint4*)(resB + (size_t)(row0 + (l >> 2)) * 128 + (l & 3) * 32);
        #pragma unroll
        for (int t = 0; t < 4; ++t) gb[t] = sb[l * 4 + t];
      }
      asm volatile("s_waitcnt lgkmcnt(0)" ::: "memory");
    }
  }
}

// layers 1/2 GEMM: A bf16 [N][128] @ Wp(LDS-shared) -> fp8 h'
__global__ __launch_bounds__(256) void k_gemm8(const uint16_t* __restrict__ A,
                                               const uint16_t* __restrict__ Wp,
                                               uint8_t* __restrict__ H8,
                                               const float* __restrict__ dinv) {
  __shared__ __align__(16) char smem[32768];
  int tid = threadIdx.x, wid = tid >> 6, l = tid & 63;
  #pragma unroll
  for (int i = 0; i < 8; ++i) {
    int gidx = i * 256 + tid;
    *(uint4*)(smem + gidx * 16) = *(const uint4*)((const char*)Wp + gidx * 16);
  }
  __syncthreads();
  int r0 = blockIdx.x * 128 + wid * 32;
  int hk = l >> 4, rl = l & 15;
  int ra0 = min(r0 + rl, N_NODES - 1);
  int ra1 = min(r0 + 16 + rl, N_NODES - 1);
  f32x4 acc[2][8] = {};
  #pragma unroll
  for (int ks = 0; ks < 4; ++ks) {
    bf16x8 a0 = *(const bf16x8*)(A + (size_t)ra0 * 128 + ks * 32 + hk * 8);
    bf16x8 a1 = *(const bf16x8*)(A + (size_t)ra1 * 128 + ks * 32 + hk * 8);
    #pragma unroll
    for (int nt = 0; nt < 8; ++nt) {
      bf16x8 b = *(const bf16x8*)(smem + ((ks * 8 + nt) * 64 + l) * 16);
      acc[0][nt] = __builtin_amdgcn_mfma_f32_16x16x32_bf16(a0, b, acc[0][nt], 0, 0, 0);
      acc[1][nt] = __builtin_amdgcn_mfma_f32_16x16x32_bf16(a1, b, acc[1][nt], 0, 0, 0);
    }
  }
  __syncthreads();  // B dead; reuse as epilogue scratch
  uint8_t* lds8 = (uint8_t*)(smem + wid * 4096);
  epilogue_fp8(acc[0], l, r0, lds8, H8, dinv);
  epilogue_fp8(acc[1], l, r0 + 16, lds8, H8, dinv);
}

// fused: fp8 gather-sum + bias + LN + ReLU + bf16 residual
// four 16-lane quarters; quarter q owns 4-edge blocks jb%4==q (uint4 index loads);
// lane owns 8 channels (uint2 gather); unweighted fp8 row sum (scales pre-folded).
#define PROC(hx, hy)                                                   \
  do {                                                                 \
    f32x2 f_;                                                          \
    f_ = __builtin_amdgcn_cvt_pk_f32_fp8((hx), false);                 \
    asm("v_pk_add_f32 %0, %0, %1" : "+v"(A01) : "v"(f_));              \
    f_ = __builtin_amdgcn_cvt_pk_f32_fp8((hx), true);                  \
    asm("v_pk_add_f32 %0, %0, %1" : "+v"(A23) : "v"(f_));              \
    f_ = __builtin_amdgcn_cvt_pk_f32_fp8((hy), false);                 \
    asm("v_pk_add_f32 %0, %0, %1" : "+v"(A45) : "v"(f_));              \
    f_ = __builtin_amdgcn_cvt_pk_f32_fp8((hy), true);                  \
    asm("v_pk_add_f32 %0, %0, %1" : "+v"(A67) : "v"(f_));              \
  } while (0)

__global__ __launch_bounds__(256) void k_agg(const uint8_t* __restrict__ H8,
                                             const int* __restrict__ sedge,
                                             const int2* __restrict__ offs2,
                                             const float* __restrict__ dinv,
                                             const float* __restrict__ bias,
                                             const float* __restrict__ g,
                                             const float* __restrict__ be,
                                             const uint16_t* __restrict__ residB,
                                             float* __restrict__ outF,
                                             uint16_t* __restrict__ outB) {
  int wid = threadIdx.x >> 6, l = threadIdx.x & 63;
  int v = blockIdx.x * 4 + wid;
  if (v >= N_NODES) return;
  int q = l >> 4, c = l & 15;
  uint32_t coff = (uint32_t)c << 3;
  f32x2 A01 = {0.f, 0.f}, A23 = {0.f, 0.f}, A45 = {0.f, 0.f}, A67 = {0.f, 0.f};
  int2 o = offs2[v];
  int nb = o.y;                          // 4-edge blocks (padded, exact)
  const uint4* sblk = (const uint4*)(sedge + o.x);
  int jb = q;
  for (; jb + 4 < nb; jb += 8) {
    uint4 i0 = sblk[jb];
    uint4 i1 = sblk[jb + 4];
    uint2 h0 = *(const uint2*)(H8 + ((i0.x << 7) | coff));
    uint2 h1 = *(const uint2*)(H8 + ((i0.y << 7) | coff));
    uint2 h2 = *(const uint2*)(H8 + ((i0.z << 7) | coff));
    uint2 h3 = *(const uint2*)(H8 + ((i0.w << 7) | coff));
    uint2 h4 = *(const uint2*)(H8 + ((i1.x << 7) | coff));
    uint2 h5 = *(const uint2*)(H8 + ((i1.y << 7) | coff));
    uint2 h6 = *(const uint2*)(H8 + ((i1.z << 7) | coff));
    uint2 h7 = *(const uint2*)(H8 + ((i1.w << 7) | coff));
    PROC(h0.x, h0.y); PROC(h1.x, h1.y); PROC(h2.x, h2.y); PROC(h3.x, h3.y);
    PROC(h4.x, h4.y); PROC(h5.x, h5.y); PROC(h6.x, h6.y); PROC(h7.x, h7.y);
  }
  for (; jb < nb; jb += 4) {
    uint4 i0 = sblk[jb];
    uint2 h0 = *(const uint2*)(H8 + ((i0.x << 7) | coff));
    uint2 h1 = *(const uint2*)(H8 + ((i0.y << 7) | coff));
    uint2 h2 = *(const uint2*)(H8 + ((i0.z << 7) | coff));
    uint2 h3 = *(const uint2*)(H8 + ((i0.w << 7) | coff));
    PROC(h0.x, h0.y); PROC(h1.x, h1.y); PROC(h2.x, h2.y); PROC(h3.x, h3.y);
  }
  if (q == 0) {  // self loop: + own h' row
    uint2 h = *(const uint2*)(H8 + (((uint32_t)v << 7) | coff));
    PROC(h.x, h.y);
  }
  // combine the 4 quarters
  float a0 = A01.x, a1 = A01.y, a2 = A23.x, a3 = A23.y;
  float a4 = A45.x, a5 = A45.y, a6 = A67.x, a7 = A67.y;
  #pragma unroll
  for (int m = 16; m <= 32; m <<= 1) {
    a0 += __shfl_xor(a0, m, 64); a1 += __shfl_xor(a1, m, 64);
    a2 += __shfl_xor(a2, m, 64); a3 += __shfl_xor(a3, m, 64);
    a4 += __shfl_xor(a4, m, 64); a5 += __shfl_xor(a5, m, 64);
    a6 += __shfl_xor(a6, m, 64); a7 += __shfl_xor(a7, m, 64);
  }
  float dv = dinv[v];
  float4 bb0 = *(const float4*)(bias + 8 * c);
  float4 bb1 = *(const float4*)(bias + 8 * c + 4);
  a0 = dv * a0 + bb0.x; a1 = dv * a1 + bb0.y;
  a2 = dv * a2 + bb0.z; a3 = dv * a3 + bb0.w;
  a4 = dv * a4 + bb1.x; a5 = dv * a5 + bb1.y;
  a6 = dv * a6 + bb1.z; a7 = dv * a7 + bb1.w;
  // LayerNorm over 128 channels (16-lane reduction, replicated across quarters)
  float s = a0 + a1 + a2 + a3 + a4 + a5 + a6 + a7;
  #pragma unroll
  for (int m = 1; m < 16; m <<= 1) s += __shfl_xor(s, m, 64);
  float mu = s * (1.f / 128.f);
  float d0 = a0 - mu, d1 = a1 - mu, d2 = a2 - mu, d3 = a3 - mu;
  float d4 = a4 - mu, d5 = a5 - mu, d6 = a6 - mu, d7 = a7 - mu;
  float qq = d0 * d0 + d1 * d1 + d2 * d2 + d3 * d3 +
             d4 * d4 + d5 * d5 + d6 * d6 + d7 * d7;
  #pragma unroll
  for (int m = 1; m < 16; m <<= 1) qq += __shfl_xor(qq, m, 64);
  float rs = rsqrtf(qq * (1.f / 128.f) + EPS);
  float4 gg0 = *(const float4*)(g + 8 * c);
  float4 gg1 = *(const float4*)(g + 8 * c + 4);
  float4 ee0 = *(const float4*)(be + 8 * c);
  float4 ee1 = *(const float4*)(be + 8 * c + 4);
  float y0 = fmaxf(d0 * rs * gg0.x + ee0.x, 0.f);
  float y1 = fmaxf(d1 * rs * gg0.y + ee0.y, 0.f);
  float y2 = fmaxf(d2 * rs * gg0.z + ee0.z, 0.f);
  float y3 = fmaxf(d3 * rs * gg0.w + ee0.w, 0.f);
  float y4 = fmaxf(d4 * rs * gg1.x + ee1.x, 0.f);
  float y5 = fmaxf(d5 * rs * gg1.y + ee1.y, 0.f);
  float y6 = fmaxf(d6 * rs * gg1.z + ee1.z, 0.f);
  float y7 = fmaxf(d7 * rs * gg1.w + ee1.w, 0.f);
  uint4 rr = *(const uint4*)(residB + (size_t)v * 128 + 8 * c);
  y0 += bflo(rr.x); y1 += bfhi(rr.x);
  y2 += bflo(rr.y); y3 += bfhi(rr.y);
  y4 += bflo(rr.z); y5 += bfhi(rr.z);
  y6 += bflo(rr.w); y7 += bfhi(rr.w);
  if (q == 0) {
    if (outF) {
      float* op = outF + (size_t)v * HID + 8 * c;
      *(float4*)op = make_float4(y0, y1, y2, y3);
      *(float4*)(op + 4) = make_float4(y4, y5, y6, y7);
    }
    if (outB) {
      uint4 oo;
      oo.x = f2bf(y0) | (f2bf(y1) << 16);
      oo.y = f2bf(y2) | (f2bf(y3) << 16);
      oo.z = f2bf(y4) | (f2bf(y5) << 16);
      oo.w = f2bf(y6) | (f2bf(y7) << 16);
      *(uint4*)(outB + (size_t)v * 128 + 8 * c) = oo;
    }
  }
}

extern "C" void kernel_launch(void* const* d_in, const int* in_sizes, int n_in,
                              void* d_out, int out_size, void* d_ws, size_t ws_size,
                              hipStream_t stream) {
  const float* x   = (const float*)d_in[0];
  const void*  ei  = d_in[1];
  const float* W0  = (const float*)d_in[2];
  const float* b0  = (const float*)d_in[3];
  const float* g0  = (const float*)d_in[4];
  const float* be0 = (const float*)d_in[5];
  const float* W1  = (const float*)d_in[6];
  const float* b1  = (const float*)d_in[7];
  const float* g1  = (const float*)d_in[8];
  const float* be1 = (const float*)d_in[9];
  const float* W2  = (const float*)d_in[10];
  const float* b2  = (const float*)d_in[11];
  const float* g2  = (const float*)d_in[12];
  const float* be2 = (const float*)d_in[13];
  const float* Wr  = (const float*)d_in[14];

  char* ws = (char*)d_ws;
  int*      sedge  = (int*)(ws + OFF_SRC);
  int2*     offs2  = (int2*)(ws + OFF_OFFS2);
  float*    dinv   = (float*)(ws + OFF_DINV);
  uint16_t* wpk0   = (uint16_t*)(ws + OFF_WPK0);
  uint16_t* wpk1   = (uint16_t*)(ws + OFF_WPK1);
  uint16_t* wpk2   = (uint16_t*)(ws + OFF_WPK2);
  uint16_t* wpkr   = (uint16_t*)(ws + OFF_WPKR);
  int*      flag   = (int*)(ws + OFF_FLAG);
  int*      bcur   = (int*)(ws + OFF_BCUR);
  uint8_t*  h8     = (uint8_t*)(ws + OFF_H8);
  int2*     part   = (int2*)(ws + OFF_PART);
  uint16_t* resB   = (uint16_t*)(ws + OFF_RESB);
  uint16_t* hbA    = (uint16_t*)(ws + OFF_HBA);
  uint16_t* hbB    = (uint16_t*)(ws + OFF_HBB);
  float*    out    = (float*)d_out;

  // ---- edge preprocessing: partition (fixed-cap buckets) -> fused bucket CSR ----
  k_flag<<<1, 256, 0, stream>>>((const uint32_t*)ei, flag);
  k_init<<<1, 256, 0, stream>>>(bcur);
  k_part<<<(N_EDGES + PCHUNK - 1) / PCHUNK, 256, 0, stream>>>(ei, flag, bcur, part);
  k_bucket<<<NBUK, 256, 0, stream>>>(part, bcur, offs2, dinv, sedge);
  // sentinel row (src == N_NODES) must be zero; part buffer is dead now
  hipMemsetAsync(h8 + (size_t)N_NODES * 128, 0, 128, stream);

  // ---- weight packing ----
  k_packW<<<16, 256, 0, stream>>>(W0, wpk0, IN_CH);
  k_packW<<<8, 256, 0, stream>>>(W1, wpk1, HID);
  k_packW<<<8, 256, 0, stream>>>(W2, wpk2, HID);
  k_packW<<<16, 256, 0, stream>>>(Wr, wpkr, IN_CH);

  // ---- layer 0: fused dual K=256 GEMM launch (x@W0 -> fp8 h', x@Wr -> bf16 resid) ----
  k_gemm0d<<<2 * GEMM_GRID, 256, 0, stream>>>(x, wpk0, wpkr, h8, dinv, resB);
  k_agg<<<25000, 256, 0, stream>>>(h8, sedge, offs2, dinv, b0, g0, be0, resB, nullptr, hbA);

  // ---- layer 1 ----
  k_gemm8<<<GEMM_GRID, 256, 0, stream>>>(hbA, wpk1, h8, dinv);
  k_agg<<<25000, 256, 0, stream>>>(h8, sedge, offs2, dinv, b1, g1, be1, hbA, nullptr, hbB);

  // ---- layer 2 (writes d_out f32) ----
  k_gemm8<<<GEMM_GRID, 256, 0, stream>>>(hbB, wpk2, h8, dinv);
  k_agg<<<25000, 256, 0, stream>>>(h8, sedge, offs2, dinv, b2, g2, be2, hbB, out, nullptr);

  (void)in_sizes; (void)n_in; (void)out_size; (void)ws_size;
}